// Round 4
// baseline (5196.482 us; speedup 1.0000x reference)
//
#include <hip/hip_runtime.h>
#include <hip/hip_bf16.h>
#include <math.h>

typedef __hip_bfloat16 bf16;
typedef __attribute__((ext_vector_type(8))) short frag8;
typedef __attribute__((ext_vector_type(4))) float f32x4;
typedef long long ll;

__device__ __forceinline__ float b2f(bf16 v) { return __bfloat162float(v); }
__device__ __forceinline__ bf16 f2b(float v) { return __float2bfloat16(v); }

#define LN_EPS 1e-5f
#define D_EPS 1e-8f
#define INV_SQRT_M 0.17677669529663687f

// ---------------- dtype sniffer: mode=1 if d_in[0] is float32, 0 if bf16 -------------
__global__ __launch_bounds__(256) void k_sniff(const void* x, int* mode)
{
    __shared__ int cnt;
    if (threadIdx.x == 0) cnt = 0;
    __syncthreads();
    const unsigned short* u = (const unsigned short*)x;
    const unsigned short h = u[2 * threadIdx.x];   // even-indexed bf16 slot
    const unsigned int bits = ((unsigned int)h) << 16;
    const float v = __uint_as_float(bits);
    const float a = fabsf(v);
    const bool sane = (h == 0) || (a >= 1e-8f && a <= 1e4f);
    if (!sane) atomicAdd(&cnt, 1);
    __syncthreads();
    if (threadIdx.x == 0) *mode = (cnt > 64) ? 1 : 0;
}

// ---------------- generic input -> bf16 convert ----------------
__global__ __launch_bounds__(256) void k_convert(const void* src, bf16* dst, int n,
                                                 const int* mode)
{
    const int i = blockIdx.x * 256 + threadIdx.x;
    if (i >= n) return;
    if (*mode) dst[i] = f2b(((const float*)src)[i]);
    else       dst[i] = ((const bf16*)src)[i];
}

// ---- pad p1_kqv_w [192,27] -> [192,32], with dtype convert ----
__global__ __launch_bounds__(256) void k_padw(const void* src, bf16* dst, const int* mode)
{
    const int i = blockIdx.x * 256 + threadIdx.x;    // < 6144
    const int o = i >> 5, d = i & 31;
    float v = 0.f;
    if (d < 27) {
        if (*mode) v = ((const float*)src)[o * 27 + d];
        else       v = b2f(((const bf16*)src)[o * 27 + d]);
    }
    dst[i] = f2b(v);
}

__global__ __launch_bounds__(256) void k_zero(float* p, int n)
{
    const int i = blockIdx.x * 256 + threadIdx.x;
    if (i < n) p[i] = 0.f;
}

// ---- stage-1: unfold 3x3 s1 p1 over one batch of [3,224,224] + LN(27), K padded to 32
__global__ __launch_bounds__(256) void k_unfold27(
    const bf16* __restrict__ x, const bf16* __restrict__ g,
    const bf16* __restrict__ bb, bf16* __restrict__ A, const int b)
{
    const int t = blockIdx.x * 256 + threadIdx.x;    // < 50176
    const int h = t / 224;
    const int w = t - h * 224;
    float tv[27];
    #pragma unroll
    for (int c = 0; c < 3; ++c)
        #pragma unroll
        for (int i = 0; i < 3; ++i)
            #pragma unroll
            for (int j = 0; j < 3; ++j) {
                const int hh = h + i - 1, ww = w + j - 1;
                float val = 0.f;
                if (hh >= 0 && hh < 224 && ww >= 0 && ww < 224)
                    val = b2f(x[((ll)(b * 3 + c) * 224 + hh) * 224 + ww]);
                tv[c * 9 + i * 3 + j] = val;
            }
    float s = 0.f;
    #pragma unroll
    for (int d = 0; d < 27; ++d) s += tv[d];
    const float mean = s * (1.f / 27.f);
    float s2 = 0.f;
    #pragma unroll
    for (int d = 0; d < 27; ++d) { const float dd = tv[d] - mean; s2 += dd * dd; }
    const float rs = rsqrtf(s2 * (1.f / 27.f) + LN_EPS);
    bf16* out = A + (ll)t * 32;
    #pragma unroll
    for (int d = 0; d < 27; ++d)
        out[d] = f2b((tv[d] - mean) * rs * b2f(g[d]) + b2f(bb[d]));
    #pragma unroll
    for (int d = 27; d < 32; ++d) out[d] = f2b(0.f);
}

// ---- unfold 3x3 s2 p1 over single-batch token-major [Hin*Hin,64] (+ optional LN(576))
__global__ __launch_bounds__(64) void k_unfold576(
    const bf16* __restrict__ in, const int Hin, const int Ho,
    const bf16* __restrict__ g, const bf16* __restrict__ bb,
    const int do_ln, bf16* __restrict__ A)
{
    const int t = blockIdx.x;
    const int l = threadIdx.x;
    const int ho = t / Ho, wo = t - ho * Ho;
    float vals[9];
    float s = 0.f;
    #pragma unroll
    for (int r = 0; r < 9; ++r) {
        const int d = l + (r << 6);
        const int c = d / 9;
        const int rr = d - c * 9;
        const int i = rr / 3, j = rr - i * 3;
        const int hh = 2 * ho + i - 1, ww = 2 * wo + j - 1;
        float val = 0.f;
        if (hh >= 0 && hh < Hin && ww >= 0 && ww < Hin)
            val = b2f(in[((ll)hh * Hin + ww) * 64 + c]);
        vals[r] = val; s += val;
    }
    bf16* out = A + (ll)t * 576;
    if (do_ln) {
        #pragma unroll
        for (int o = 32; o > 0; o >>= 1) s += __shfl_xor(s, o, 64);
        const float mean = s * (1.f / 576.f);
        float s2 = 0.f;
        #pragma unroll
        for (int r = 0; r < 9; ++r) { const float dd = vals[r] - mean; s2 += dd * dd; }
        #pragma unroll
        for (int o = 32; o > 0; o >>= 1) s2 += __shfl_xor(s2, o, 64);
        const float rs = rsqrtf(s2 * (1.f / 576.f) + LN_EPS);
        #pragma unroll
        for (int r = 0; r < 9; ++r) {
            const int d = l + (r << 6);
            out[d] = f2b((vals[r] - mean) * rs * b2f(g[d]) + b2f(bb[d]));
        }
    } else {
        #pragma unroll
        for (int r = 0; r < 9; ++r) out[l + (r << 6)] = f2b(vals[r]);
    }
}

// ---- MFMA bf16 GEMM: C[M,N] = A[M,K](lda) @ W[N,K]^T + bias (+res) ----
// BM=64, BN=64, BK=32. grid (M/64, N/64). C row index gets +mOff (global offset).
// res may alias C (same-thread read-then-write). If outm && *outm==1, C is float32.
__global__ __launch_bounds__(256) void k_gemm(
    const bf16* __restrict__ A, const int lda,
    const bf16* __restrict__ W,
    const bf16* __restrict__ bias,
    const bf16* res, const int ldres,
    void* C, const int ldc, const ll mOff,
    const int K, const int* outm)
{
    __shared__ bf16 As[64][40];
    __shared__ bf16 Bs[64][40];
    const int tid = threadIdx.x;
    const int wv = tid >> 6;
    const int lane = tid & 63;

    const ll m0 = (ll)blockIdx.x * 64;
    const int n0 = blockIdx.y * 64;

    f32x4 acc[4] = {};

    const int lr = tid >> 2;
    const int lc = (tid & 3) << 3;
    const int mr = (wv << 4) + (lane & 15);
    const int k8 = (lane >> 4) << 3;
    const bf16* Ag = A + (m0 + lr) * (ll)lda + lc;
    const bf16* Wg = W + (ll)(n0 + lr) * K + lc;

    for (int k0 = 0; k0 < K; k0 += 32) {
        const uint4 av = *(const uint4*)(Ag + k0);
        *(uint4*)(&As[lr][lc]) = av;
        const uint4 wv4 = *(const uint4*)(Wg + k0);
        *(uint4*)(&Bs[lr][lc]) = wv4;
        __syncthreads();
        const frag8 af = *(const frag8*)(&As[mr][k8]);
        #pragma unroll
        for (int tn = 0; tn < 4; ++tn) {
            const frag8 bfv = *(const frag8*)(&Bs[(tn << 4) + (lane & 15)][k8]);
            acc[tn] = __builtin_amdgcn_mfma_f32_16x16x32_bf16(af, bfv, acc[tn], 0, 0, 0);
        }
        __syncthreads();
    }

    const int om = outm ? *outm : 0;
    const int rbase = (lane >> 4) << 2;
    #pragma unroll
    for (int tn = 0; tn < 4; ++tn) {
        const int n = n0 + (tn << 4) + (lane & 15);
        const float bv = bias ? b2f(bias[n]) : 0.f;
        #pragma unroll
        for (int r = 0; r < 4; ++r) {
            const ll m = m0 + (wv << 4) + rbase + r;
            float v = acc[tn][r] + bv;
            if (res) v += b2f(res[m * (ll)ldres + n]);
            const ll ci = (m + mOff) * (ll)ldc + n;
            if (om) ((float*)C)[ci] = v;
            else    ((bf16*)C)[ci] = f2b(v);
        }
    }
}

// ---- fused prm_exp: out = exp(x@w^T - |x|^2/2)/sqrt(32); one thread per token ----
__global__ __launch_bounds__(256) void k_pexp2(
    const bf16* __restrict__ X, const int xstride,
    const bf16* __restrict__ w, bf16* __restrict__ out)
{
    __shared__ float wsm[32][65];
    const int tid = threadIdx.x;
    for (int i = tid; i < 2048; i += 256) {
        const int m = i >> 6, e = i & 63;
        wsm[m][e] = b2f(w[i]);
    }
    __syncthreads();
    const ll idx = (ll)blockIdx.x * 256 + tid;
    const bf16* row = X + idx * xstride;
    float x[64];
    float xd = 0.f;
    #pragma unroll
    for (int e = 0; e < 64; ++e) { x[e] = b2f(row[e]); xd += x[e] * x[e]; }
    xd *= 0.5f;
    #pragma unroll 4
    for (int m = 0; m < 32; ++m) {
        float s = 0.f;
        #pragma unroll
        for (int e = 0; e < 64; ++e) s += x[e] * wsm[m][e];
        out[idx * 32 + m] = f2b(expf(fminf(s - xd, 30.f)) * INV_SQRT_M);
    }
}

// ---- single-batch reduce: red[n*32+m] = sum_t v[t][n]*kp[t][m]; red[2048+m]=sum kp
__global__ __launch_bounds__(256) void k_reduce(
    const bf16* __restrict__ kp, const bf16* __restrict__ v, const int vstride,
    const int T, float* __restrict__ red)
{
    __shared__ float kps[64][33];
    __shared__ float vs[64][65];
    const int tid = threadIdx.x;
    const int m = tid & 31, n8 = tid >> 5;
    float acc[8] = {0.f, 0.f, 0.f, 0.f, 0.f, 0.f, 0.f, 0.f};
    float ksum = 0.f;
    const int t0 = blockIdx.x * 1024;
    for (int tt = 0; tt < 1024; tt += 64) {
        __syncthreads();
        #pragma unroll
        for (int i = 0; i < 8; ++i) {
            const int li = tid + i * 256;
            const int tok = li >> 5, mm = li & 31;
            const int gt = t0 + tt + tok;
            kps[tok][mm] = (gt < T) ? b2f(kp[(ll)gt * 32 + mm]) : 0.f;
        }
        #pragma unroll
        for (int i = 0; i < 16; ++i) {
            const int li = tid + i * 256;
            const int tok = li >> 6, nn = li & 63;
            const int gt = t0 + tt + tok;
            vs[tok][nn] = (gt < T) ? b2f(v[(ll)gt * vstride + nn]) : 0.f;
        }
        __syncthreads();
        #pragma unroll 8
        for (int tok = 0; tok < 64; ++tok) {
            const float kv = kps[tok][m];
            ksum += kv;
            #pragma unroll
            for (int r = 0; r < 8; ++r)
                acc[r] += vs[tok][n8 * 8 + r] * kv;
        }
    }
    #pragma unroll
    for (int r = 0; r < 8; ++r)
        atomicAdd(&red[(n8 * 8 + r) * 32 + m], acc[r]);
    if (n8 == 0) atomicAdd(&red[2048 + m], ksum);
}

// ---- convert fp32 red[0..2048) -> bf16 kptv ----
__global__ __launch_bounds__(256) void k_redconv(const float* __restrict__ red,
                                                 bf16* __restrict__ kptv)
{
    const int i = blockIdx.x * 256 + threadIdx.x;    // < 2048
    kptv[i] = f2b(red[i]);
}

// ---- per-token scale: y0[t] /= (qp[t] . ksum + eps) ----
__global__ __launch_bounds__(256) void k_dscale(
    const bf16* __restrict__ qp, const float* __restrict__ red,
    bf16* __restrict__ y0)
{
    const ll t = (ll)blockIdx.x * 256 + threadIdx.x;
    const float* ks = red + 2048;
    float D = D_EPS;
    #pragma unroll
    for (int m = 0; m < 32; ++m) D += b2f(qp[t * 32 + m]) * ks[m];
    const float inv = 1.f / D;
    #pragma unroll
    for (int n = 0; n < 64; ++n)
        y0[t * 64 + n] = f2b(b2f(y0[t * 64 + n]) * inv);
}

// ---- LayerNorm over 64 channels (token-major) ----
__global__ __launch_bounds__(256) void k_ln64(
    const bf16* __restrict__ y, const bf16* __restrict__ g,
    const bf16* __restrict__ bb, bf16* __restrict__ h2)
{
    const ll idx = (ll)blockIdx.x * 256 + threadIdx.x;
    float v[64];
    float s = 0.f;
    #pragma unroll
    for (int n = 0; n < 64; ++n) { v[n] = b2f(y[idx * 64 + n]); s += v[n]; }
    const float mean = s * (1.f / 64.f);
    float s2 = 0.f;
    #pragma unroll
    for (int n = 0; n < 64; ++n) { const float d = v[n] - mean; s2 += d * d; }
    const float rs = rsqrtf(s2 * (1.f / 64.f) + LN_EPS);
    #pragma unroll
    for (int n = 0; n < 64; ++n)
        h2[idx * 64 + n] = f2b((v[n] - mean) * rs * b2f(g[n]) + b2f(bb[n]));
}

// ---- fused MLP: out = res + (gelu(H@w1^T + b1)) @ w2^T + b2, all 64x64 ----
__global__ __launch_bounds__(256) void k_mlp(
    const bf16* __restrict__ H, const bf16* __restrict__ w1, const bf16* __restrict__ b1,
    const bf16* __restrict__ w2, const bf16* __restrict__ b2,
    const bf16* res, bf16* out)
{
    __shared__ bf16 Hs[64][72];
    __shared__ bf16 W1s[64][72];
    __shared__ bf16 W2s[64][72];
    __shared__ bf16 Gs[64][72];
    const int tid = threadIdx.x;
    const int wv = tid >> 6, lane = tid & 63;
    const ll m0 = (ll)blockIdx.x * 64;
    const int lr = tid >> 2;
    const int lc = (tid & 3) << 4;
    *(uint4*)(&Hs[lr][lc])      = *(const uint4*)(H + (m0 + lr) * 64 + lc);
    *(uint4*)(&Hs[lr][lc + 8])  = *(const uint4*)(H + (m0 + lr) * 64 + lc + 8);
    *(uint4*)(&W1s[lr][lc])     = *(const uint4*)(w1 + lr * 64 + lc);
    *(uint4*)(&W1s[lr][lc + 8]) = *(const uint4*)(w1 + lr * 64 + lc + 8);
    *(uint4*)(&W2s[lr][lc])     = *(const uint4*)(w2 + lr * 64 + lc);
    *(uint4*)(&W2s[lr][lc + 8]) = *(const uint4*)(w2 + lr * 64 + lc + 8);
    __syncthreads();
    const int mr = (wv << 4) + (lane & 15);
    const int k8 = (lane >> 4) << 3;
    const int rbase = (lane >> 4) << 2;
    f32x4 acc[4] = {};
    #pragma unroll
    for (int k0 = 0; k0 < 64; k0 += 32) {
        const frag8 af = *(const frag8*)(&Hs[mr][k8 + k0]);
        #pragma unroll
        for (int tn = 0; tn < 4; ++tn) {
            const frag8 bfv = *(const frag8*)(&W1s[(tn << 4) + (lane & 15)][k8 + k0]);
            acc[tn] = __builtin_amdgcn_mfma_f32_16x16x32_bf16(af, bfv, acc[tn], 0, 0, 0);
        }
    }
    #pragma unroll
    for (int tn = 0; tn < 4; ++tn) {
        const int n = (tn << 4) + (lane & 15);
        const float bv = b2f(b1[n]);
        #pragma unroll
        for (int r = 0; r < 4; ++r) {
            float v = acc[tn][r] + bv;
            v = 0.5f * v * (1.f + erff(v * 0.70710678118654752f));
            Gs[(wv << 4) + rbase + r][n] = f2b(v);
        }
    }
    __syncthreads();
    f32x4 acc2[4] = {};
    #pragma unroll
    for (int k0 = 0; k0 < 64; k0 += 32) {
        const frag8 af = *(const frag8*)(&Gs[mr][k8 + k0]);
        #pragma unroll
        for (int tn = 0; tn < 4; ++tn) {
            const frag8 bfv = *(const frag8*)(&W2s[(tn << 4) + (lane & 15)][k8 + k0]);
            acc2[tn] = __builtin_amdgcn_mfma_f32_16x16x32_bf16(af, bfv, acc2[tn], 0, 0, 0);
        }
    }
    #pragma unroll
    for (int tn = 0; tn < 4; ++tn) {
        const int n = (tn << 4) + (lane & 15);
        const float bv = b2f(b2[n]);
        #pragma unroll
        for (int r = 0; r < 4; ++r) {
            const ll m = m0 + (wv << 4) + rbase + r;
            out[m * 64 + n] = f2b(acc2[tn][r] + bv + b2f(res[m * 64 + n]));
        }
    }
}

extern "C" void kernel_launch(void* const* d_in, const int* in_sizes, int n_in,
                              void* d_out, int out_size, void* d_ws, size_t ws_size,
                              hipStream_t stream)
{
    (void)in_sizes; (void)n_in; (void)out_size; (void)ws_size;
    const int T1 = 50176, T2 = 12544;
    char* ws = (char*)d_ws;

    // ---- converted-input block (bf16 in ws), 0 .. 3,670,016 ----
    bf16* XC     = (bf16*)(ws + 0);            // 1,204,224 el
    bf16* W1P    = (bf16*)(ws + 2408448);      // [192,32] padded
    bf16* P1KQVB = (bf16*)(ws + 2420736);
    bf16* P1PW   = (bf16*)(ws + 2421760);
    bf16* P1PB   = (bf16*)(ws + 2429952);
    bf16* P1N1G  = (bf16*)(ws + 2430976);
    bf16* P1N1B  = (bf16*)(ws + 2432000);
    bf16* P1N2G  = (bf16*)(ws + 2433024);
    bf16* P1N2B  = (bf16*)(ws + 2434048);
    bf16* P1M1W  = (bf16*)(ws + 2435072);
    bf16* P1M1B  = (bf16*)(ws + 2443264);
    bf16* P1M2W  = (bf16*)(ws + 2444288);
    bf16* P1M2B  = (bf16*)(ws + 2452480);
    bf16* P1W    = (bf16*)(ws + 2453504);
    bf16* P2KQVW = (bf16*)(ws + 2457600);
    bf16* P2KQVB = (bf16*)(ws + 2678784);
    bf16* P2PW   = (bf16*)(ws + 2679808);
    bf16* P2PB   = (bf16*)(ws + 2688000);
    bf16* P2N1G  = (bf16*)(ws + 2689024);
    bf16* P2N1B  = (bf16*)(ws + 2691072);
    bf16* P2N2G  = (bf16*)(ws + 2693120);
    bf16* P2N2B  = (bf16*)(ws + 2694144);
    bf16* P2M1W  = (bf16*)(ws + 2695168);
    bf16* P2M1B  = (bf16*)(ws + 2703360);
    bf16* P2M2W  = (bf16*)(ws + 2704384);
    bf16* P2M2B  = (bf16*)(ws + 2712576);
    bf16* P2W    = (bf16*)(ws + 2713600);
    bf16* PROJW  = (bf16*)(ws + 2717696);
    bf16* PROJB  = (bf16*)(ws + 3602432);
    int*  MODE   = (int*) (ws + 3604480);
    float* RED   = (float*)(ws + 3604736);     // 2112 floats
    bf16* KPTV   = (bf16*)(ws + 3613184);      // 2048 el

    // ---- per-batch buffers, lifetime-overlapped; peak ws end = 24,543,232 B ----
    // Base B = 3,670,016. Stage-1 timeline: A1(u27)->BIG(K)->KP->BIG(Q)->QP->BIG(V)
    //   ->reduce->Y0->dscale->projGEMM(BIG in-place)->ln64(H1)->mlp(BIG in-place).
    // Stage-2: unfold(BIG->A2) -> kqv(A2->KQV2, overlays dead BIG) -> pexp(KP2,QP2)
    //   -> reduce -> Y02/YB2/H2/A3 overlay dead A2 -> proj -> d_out.
    bf16* A1   = (bf16*)(ws + 3670016);        // [T1,32]  3,211,264 B
    bf16* KP   = (bf16*)(ws + 6881280);        // [T1,32]
    bf16* QP   = (bf16*)(ws + 10092544);       // [T1,32]
    bf16* Y0   = (bf16*)(ws + 3670016);        // [T1,64]  over A1+KP (dead)
    bf16* H1   = (bf16*)(ws + 3670016);        // [T1,64]  over Y0 (dead)
    bf16* A2   = (bf16*)(ws + 3670016);        // [T2,576] 14,450,688 B (stage-1 smalls dead)
    bf16* BIG  = (bf16*)(ws + 18120704);       // [T1,64]  6,422,528 B; ends 24,543,232
    bf16* KQV2 = (bf16*)(ws + 18120704);       // [T2,192] 4,816,896 B over BIG (dead)
    bf16* KP2  = (bf16*)(ws + 22937600);       // [T2,32]  802,816 B
    bf16* QP2  = (bf16*)(ws + 23740416);       // [T2,32]  ends 24,543,232
    bf16* Y02  = (bf16*)(ws + 3670016);        // [T2,64]  over A2 (dead)
    bf16* YB2  = (bf16*)(ws + 5275648);        // [T2,64]
    bf16* H2   = (bf16*)(ws + 6881280);        // [T2,64]
    bf16* A3   = (bf16*)(ws + 8486912);        // [3136,576] 3,612,672 B; ends 12,099,584

    // ---- dtype sniff + convert all inputs to bf16 in ws ----
    k_sniff<<<1, 256, 0, stream>>>(d_in[0], MODE);
    struct CvEnt { int idx; bf16* dst; int n; };
    const CvEnt cv[] = {
        {0, XC, 1204224},
        {2, P1KQVB, 192}, {3, P1PW, 4096}, {4, P1PB, 64},
        {5, P1N1G, 27}, {6, P1N1B, 27}, {7, P1N2G, 64}, {8, P1N2B, 64},
        {9, P1M1W, 4096}, {10, P1M1B, 64}, {11, P1M2W, 4096}, {12, P1M2B, 64},
        {13, P1W, 2048},
        {14, P2KQVW, 110592}, {15, P2KQVB, 192}, {16, P2PW, 4096}, {17, P2PB, 64},
        {18, P2N1G, 576}, {19, P2N1B, 576}, {20, P2N2G, 64}, {21, P2N2B, 64},
        {22, P2M1W, 4096}, {23, P2M1B, 64}, {24, P2M2W, 4096}, {25, P2M2B, 64},
        {26, P2W, 2048},
        {27, PROJW, 442368}, {28, PROJB, 768},
    };
    for (int c = 0; c < (int)(sizeof(cv) / sizeof(cv[0])); ++c)
        k_convert<<<(cv[c].n + 255) / 256, 256, 0, stream>>>(
            d_in[cv[c].idx], cv[c].dst, cv[c].n, MODE);
    k_padw<<<24, 256, 0, stream>>>(d_in[1], W1P, MODE);

    for (int b = 0; b < 8; ++b) {
        // ============ stage 1 (dim 27) ============
        k_unfold27<<<196, 256, 0, stream>>>(XC, P1N1G, P1N1B, A1, b);
        k_gemm<<<dim3(784, 1), 256, 0, stream>>>(A1, 32, W1P, P1KQVB,
            nullptr, 0, BIG, 64, 0, 32, nullptr);                    // K
        k_pexp2<<<196, 256, 0, stream>>>(BIG, 64, P1W, KP);
        k_gemm<<<dim3(784, 1), 256, 0, stream>>>(A1, 32, W1P + 64 * 32, P1KQVB + 64,
            nullptr, 0, BIG, 64, 0, 32, nullptr);                    // Q
        k_pexp2<<<196, 256, 0, stream>>>(BIG, 64, P1W, QP);
        k_gemm<<<dim3(784, 1), 256, 0, stream>>>(A1, 32, W1P + 128 * 32, P1KQVB + 128,
            nullptr, 0, BIG, 64, 0, 32, nullptr);                    // V (stays in BIG)
        k_zero<<<9, 256, 0, stream>>>(RED, 2112);
        k_reduce<<<49, 256, 0, stream>>>(KP, BIG, 64, T1, RED);
        k_redconv<<<8, 256, 0, stream>>>(RED, KPTV);
        k_gemm<<<dim3(784, 1), 256, 0, stream>>>(QP, 32, KPTV, nullptr,
            nullptr, 0, Y0, 64, 0, 32, nullptr);                     // y0 = qp @ kptv^T
        k_dscale<<<196, 256, 0, stream>>>(QP, RED, Y0);
        k_gemm<<<dim3(784, 1), 256, 0, stream>>>(Y0, 64, P1PW, P1PB,
            BIG, 64, BIG, 64, 0, 64, nullptr);                       // Yb1 = V + proj(y)
        k_ln64<<<196, 256, 0, stream>>>(BIG, P1N2G, P1N2B, H1);
        k_mlp<<<784, 256, 0, stream>>>(H1, P1M1W, P1M1B, P1M2W, P1M2B, BIG, BIG);

        // ============ stage 2 (dim 576) ============
        k_unfold576<<<12544, 64, 0, stream>>>(BIG, 224, 112, P2N1G, P2N1B, 1, A2);
        k_gemm<<<dim3(196, 3), 256, 0, stream>>>(A2, 576, P2KQVW, P2KQVB,
            nullptr, 0, KQV2, 192, 0, 576, nullptr);
        k_pexp2<<<49, 256, 0, stream>>>(KQV2, 192, P2W, KP2);
        k_pexp2<<<49, 256, 0, stream>>>(KQV2 + 64, 192, P2W, QP2);
        k_zero<<<9, 256, 0, stream>>>(RED, 2112);
        k_reduce<<<13, 256, 0, stream>>>(KP2, KQV2 + 128, 192, T2, RED);
        k_redconv<<<8, 256, 0, stream>>>(RED, KPTV);
        k_gemm<<<dim3(196, 1), 256, 0, stream>>>(QP2, 32, KPTV, nullptr,
            nullptr, 0, Y02, 64, 0, 32, nullptr);
        k_dscale<<<49, 256, 0, stream>>>(QP2, RED, Y02);
        k_gemm<<<dim3(196, 1), 256, 0, stream>>>(Y02, 64, P2PW, P2PB,
            KQV2 + 128, 192, YB2, 64, 0, 64, nullptr);               // Yb2 = V2 + proj
        k_ln64<<<49, 256, 0, stream>>>(YB2, P2N2G, P2N2B, H2);
        k_mlp<<<196, 256, 0, stream>>>(H2, P2M1W, P2M1B, P2M2W, P2M2B, YB2, YB2);

        // ============ stage 3 (unfold + final proj) ============
        k_unfold576<<<3136, 64, 0, stream>>>(YB2, 112, 56, nullptr, nullptr, 0, A3);
        k_gemm<<<dim3(49, 12), 256, 0, stream>>>(A3, 576, PROJW, PROJB,
            nullptr, 0, d_out, 768, (ll)b * 3136, 576, MODE);
    }
}

// Round 5
// 2207.508 us; speedup vs baseline: 2.3540x; 2.3540x over previous
//
#include <hip/hip_runtime.h>
#include <hip/hip_bf16.h>
#include <math.h>

typedef __hip_bfloat16 bf16;
typedef __attribute__((ext_vector_type(8))) short frag8;
typedef __attribute__((ext_vector_type(4))) float f32x4;
typedef long long ll;

__device__ __forceinline__ float b2f(bf16 v) { return __bfloat162float(v); }
__device__ __forceinline__ bf16 f2b(float v) { return __float2bfloat16(v); }

#define LN_EPS 1e-5f
#define D_EPS 1e-8f
#define INV_SQRT_M 0.17677669529663687f

// ---------------- dtype sniffer: mode=1 if d_in[0] is float32, 0 if bf16 -------------
__global__ __launch_bounds__(256) void k_sniff(const void* x, int* mode)
{
    __shared__ int cnt;
    if (threadIdx.x == 0) cnt = 0;
    __syncthreads();
    const unsigned short* u = (const unsigned short*)x;
    const unsigned short h = u[2 * threadIdx.x];
    const unsigned int bits = ((unsigned int)h) << 16;
    const float v = __uint_as_float(bits);
    const float a = fabsf(v);
    const bool sane = (h == 0) || (a >= 1e-8f && a <= 1e4f);
    if (!sane) atomicAdd(&cnt, 1);
    __syncthreads();
    if (threadIdx.x == 0) *mode = (cnt > 64) ? 1 : 0;
}

// ---------------- single table-driven convert of all params + x ----------------
struct CvTab { const void* src[28]; int dstOff[28]; int cum[29]; };

__global__ __launch_bounds__(256) void k_convert_all(CvTab tab, bf16* base,
                                                     const int* mode)
{
    const int idx = blockIdx.x * 256 + threadIdx.x;
    if (idx >= tab.cum[28]) return;
    int s = 0;
    while (idx >= tab.cum[s + 1]) ++s;
    const int local = idx - tab.cum[s];
    const float v = (*mode) ? ((const float*)tab.src[s])[local]
                            : b2f(((const bf16*)tab.src[s])[local]);
    base[tab.dstOff[s] + local] = f2b(v);
}

// ---- fused stage-1 front: unfold27 + LN(27) + kqv + prm_exp(k,q) ----
// grid 196 x 256thr, one thread per token. Writes KP[T1,32], QP[T1,32], V[T1,64].
// Block 0 zeroes red[2080].
__global__ __launch_bounds__(256) void k_fused1(
    const bf16* __restrict__ x, const void* __restrict__ w1raw,
    const bf16* __restrict__ kqvb, const bf16* __restrict__ n1g,
    const bf16* __restrict__ n1b, const bf16* __restrict__ pw,
    const int* __restrict__ mode,
    bf16* __restrict__ KP, bf16* __restrict__ QP, bf16* __restrict__ V,
    float* __restrict__ red, const int b)
{
    __shared__ float w1s[5184];   // [192][27]
    __shared__ float wps[2048];   // [32][64]
    __shared__ float kbs[192];
    __shared__ float gs[27], bs[27];
    const int tid = threadIdx.x;
    const int md = *mode;
    for (int i = tid; i < 5184; i += 256)
        w1s[i] = md ? ((const float*)w1raw)[i] : b2f(((const bf16*)w1raw)[i]);
    for (int i = tid; i < 2048; i += 256) wps[i] = b2f(pw[i]);
    if (tid < 192) kbs[tid] = b2f(kqvb[tid]);
    if (tid < 27) { gs[tid] = b2f(n1g[tid]); bs[tid] = b2f(n1b[tid]); }
    if (blockIdx.x == 0)
        for (int i = tid; i < 2080; i += 256) red[i] = 0.f;
    __syncthreads();

    const int t = blockIdx.x * 256 + tid;          // < 50176
    const int h = t / 224, w = t - h * 224;
    float tv[27];
    #pragma unroll
    for (int c = 0; c < 3; ++c)
        #pragma unroll
        for (int i = 0; i < 3; ++i)
            #pragma unroll
            for (int j = 0; j < 3; ++j) {
                const int hh = h + i - 1, ww = w + j - 1;
                float val = 0.f;
                if (hh >= 0 && hh < 224 && ww >= 0 && ww < 224)
                    val = b2f(x[((ll)(b * 3 + c) * 224 + hh) * 224 + ww]);
                tv[c * 9 + i * 3 + j] = val;
            }
    float s = 0.f;
    #pragma unroll
    for (int d = 0; d < 27; ++d) s += tv[d];
    const float mean = s * (1.f / 27.f);
    float s2 = 0.f;
    #pragma unroll
    for (int d = 0; d < 27; ++d) { const float dd = tv[d] - mean; s2 += dd * dd; }
    const float rs = rsqrtf(s2 * (1.f / 27.f) + LN_EPS);
    #pragma unroll
    for (int d = 0; d < 27; ++d) tv[d] = (tv[d] - mean) * rs * gs[d] + bs[d];

    float t64[64];
    // ---- K -> KP ----
    #pragma unroll
    for (int o = 0; o < 64; ++o) {
        float a = kbs[o];
        #pragma unroll
        for (int d = 0; d < 27; ++d) a += tv[d] * w1s[o * 27 + d];
        t64[o] = a;
    }
    float xd = 0.f;
    #pragma unroll
    for (int e = 0; e < 64; ++e) xd += t64[e] * t64[e];
    xd *= 0.5f;
    #pragma unroll 4
    for (int m = 0; m < 32; ++m) {
        float a = -xd;
        #pragma unroll
        for (int e = 0; e < 64; ++e) a += t64[e] * wps[m * 64 + e];
        KP[(ll)t * 32 + m] = f2b(expf(fminf(a, 30.f)) * INV_SQRT_M);
    }
    // ---- Q -> QP ----
    #pragma unroll
    for (int o = 0; o < 64; ++o) {
        float a = kbs[64 + o];
        #pragma unroll
        for (int d = 0; d < 27; ++d) a += tv[d] * w1s[(64 + o) * 27 + d];
        t64[o] = a;
    }
    xd = 0.f;
    #pragma unroll
    for (int e = 0; e < 64; ++e) xd += t64[e] * t64[e];
    xd *= 0.5f;
    #pragma unroll 4
    for (int m = 0; m < 32; ++m) {
        float a = -xd;
        #pragma unroll
        for (int e = 0; e < 64; ++e) a += t64[e] * wps[m * 64 + e];
        QP[(ll)t * 32 + m] = f2b(expf(fminf(a, 30.f)) * INV_SQRT_M);
    }
    // ---- V ----
    #pragma unroll 4
    for (int o = 0; o < 64; ++o) {
        float a = kbs[128 + o];
        #pragma unroll
        for (int d = 0; d < 27; ++d) a += tv[d] * w1s[(128 + o) * 27 + d];
        V[(ll)t * 64 + o] = f2b(a);
    }
}

// ---- reduce over tokens (batched via blockIdx.y): red[n*32+m]=sum v*kp; red[2048+m]=sum kp
__global__ __launch_bounds__(256) void k_reduce(
    const bf16* __restrict__ kpB, const bf16* __restrict__ vB, const int vstride,
    const int T, float* __restrict__ redBase, const int chunk)
{
    __shared__ float kps[64][33];
    __shared__ float vs[64][65];
    const int bz = blockIdx.y;
    const bf16* kp = kpB + (ll)bz * T * 32;
    const bf16* v  = vB + (ll)bz * T * (ll)vstride;
    float* red = redBase + (ll)bz * 2080;
    const int tid = threadIdx.x;
    const int m = tid & 31, n8 = tid >> 5;
    float acc[8] = {0.f, 0.f, 0.f, 0.f, 0.f, 0.f, 0.f, 0.f};
    float ksum = 0.f;
    const int t0 = blockIdx.x * chunk;
    for (int tt = 0; tt < chunk; tt += 64) {
        __syncthreads();
        #pragma unroll
        for (int i = 0; i < 8; ++i) {
            const int li = tid + i * 256;
            const int tok = li >> 5, mm = li & 31;
            const int gt = t0 + tt + tok;
            kps[tok][mm] = (gt < T) ? b2f(kp[(ll)gt * 32 + mm]) : 0.f;
        }
        #pragma unroll
        for (int i = 0; i < 16; ++i) {
            const int li = tid + i * 256;
            const int tok = li >> 6, nn = li & 63;
            const int gt = t0 + tt + tok;
            vs[tok][nn] = (gt < T) ? b2f(v[(ll)gt * vstride + nn]) : 0.f;
        }
        __syncthreads();
        #pragma unroll 8
        for (int tok = 0; tok < 64; ++tok) {
            const float kv = kps[tok][m];
            ksum += kv;
            #pragma unroll
            for (int r = 0; r < 8; ++r)
                acc[r] += vs[tok][n8 * 8 + r] * kv;
        }
    }
    #pragma unroll
    for (int r = 0; r < 8; ++r)
        atomicAdd(&red[(n8 * 8 + r) * 32 + m], acc[r]);
    if (n8 == 0) atomicAdd(&red[2048 + m], ksum);
}

// ---- fused post-attention: y0 = qp@kptv^T, /(D+eps), @pw^T + pb + v ----
// batched via blockIdx.y. out may alias v (same-thread RMW).
__global__ __launch_bounds__(256) void k_posta(
    const bf16* __restrict__ qpB, const float* __restrict__ redBase,
    const bf16* vB, const int vstride,
    const bf16* __restrict__ pw, const bf16* __restrict__ pb,
    bf16* outB, const int T)
{
    __shared__ float kpt[2080];
    __shared__ float pws[4096];
    __shared__ float pbs[64];
    const int tid = threadIdx.x;
    const int bz = blockIdx.y;
    const float* red = redBase + (ll)bz * 2080;
    const bf16* qp = qpB + (ll)bz * T * 32;
    const bf16* v  = vB + (ll)bz * T * (ll)vstride;
    bf16* out = outB + (ll)bz * T * 64;
    for (int i = tid; i < 2080; i += 256) kpt[i] = red[i];
    for (int i = tid; i < 4096; i += 256) pws[i] = b2f(pw[i]);
    if (tid < 64) pbs[tid] = b2f(pb[tid]);
    __syncthreads();
    const int t = blockIdx.x * 256 + tid;
    float q[32];
    #pragma unroll
    for (int m = 0; m < 32; ++m) q[m] = b2f(qp[(ll)t * 32 + m]);
    float D = D_EPS;
    #pragma unroll
    for (int m = 0; m < 32; ++m) D += q[m] * kpt[2048 + m];
    const float inv = 1.f / D;
    float y0[64];
    #pragma unroll
    for (int n = 0; n < 64; ++n) {
        float a = 0.f;
        #pragma unroll
        for (int m = 0; m < 32; ++m) a += q[m] * kpt[n * 32 + m];
        y0[n] = a * inv;
    }
    #pragma unroll 4
    for (int n = 0; n < 64; ++n) {
        float a = pbs[n];
        #pragma unroll
        for (int j = 0; j < 64; ++j) a += y0[j] * pws[n * 64 + j];
        out[(ll)t * 64 + n] = f2b(a + b2f(v[(ll)t * vstride + n]));
    }
}

// ---- fused LN(64) + MLP (MFMA): out = res + gelu(LN(H)@w1^T+b1)@w2^T+b2 ----
// H/res/out may all alias (block-disjoint rows, same-thread RMW in epilogue).
__global__ __launch_bounds__(256) void k_mlpln(
    const bf16* H, const bf16* __restrict__ n2g, const bf16* __restrict__ n2b,
    const bf16* __restrict__ w1, const bf16* __restrict__ b1,
    const bf16* __restrict__ w2, const bf16* __restrict__ b2,
    const bf16* res, bf16* out)
{
    __shared__ bf16 Hs[64][72];
    __shared__ bf16 W1s[64][72];
    __shared__ bf16 W2s[64][72];
    __shared__ bf16 Gs[64][72];
    __shared__ float mns[64], rss[64];
    const int tid = threadIdx.x;
    const int wv = tid >> 6, lane = tid & 63;
    const ll m0 = (ll)blockIdx.x * 64;
    const int lr = tid >> 2;
    const int lc = (tid & 3) << 4;
    *(uint4*)(&Hs[lr][lc])      = *(const uint4*)(H + (m0 + lr) * 64 + lc);
    *(uint4*)(&Hs[lr][lc + 8])  = *(const uint4*)(H + (m0 + lr) * 64 + lc + 8);
    *(uint4*)(&W1s[lr][lc])     = *(const uint4*)(w1 + lr * 64 + lc);
    *(uint4*)(&W1s[lr][lc + 8]) = *(const uint4*)(w1 + lr * 64 + lc + 8);
    *(uint4*)(&W2s[lr][lc])     = *(const uint4*)(w2 + lr * 64 + lc);
    *(uint4*)(&W2s[lr][lc + 8]) = *(const uint4*)(w2 + lr * 64 + lc + 8);
    __syncthreads();
    if (tid < 64) {
        float s = 0.f, s2 = 0.f;
        #pragma unroll
        for (int n = 0; n < 64; ++n) { const float vv = b2f(Hs[tid][n]); s += vv; s2 += vv * vv; }
        const float mn = s * (1.f / 64.f);
        const float var = fmaxf(s2 * (1.f / 64.f) - mn * mn, 0.f);
        mns[tid] = mn; rss[tid] = rsqrtf(var + LN_EPS);
    }
    __syncthreads();
    for (int i = tid; i < 4096; i += 256) {
        const int r = i >> 6, c = i & 63;
        Hs[r][c] = f2b((b2f(Hs[r][c]) - mns[r]) * rss[r] * b2f(n2g[c]) + b2f(n2b[c]));
    }
    __syncthreads();
    const int mr = (wv << 4) + (lane & 15);
    const int k8 = (lane >> 4) << 3;
    const int rbase = (lane >> 4) << 2;
    f32x4 acc[4] = {};
    #pragma unroll
    for (int k0 = 0; k0 < 64; k0 += 32) {
        const frag8 af = *(const frag8*)(&Hs[mr][k8 + k0]);
        #pragma unroll
        for (int tn = 0; tn < 4; ++tn) {
            const frag8 bfv = *(const frag8*)(&W1s[(tn << 4) + (lane & 15)][k8 + k0]);
            acc[tn] = __builtin_amdgcn_mfma_f32_16x16x32_bf16(af, bfv, acc[tn], 0, 0, 0);
        }
    }
    #pragma unroll
    for (int tn = 0; tn < 4; ++tn) {
        const int n = (tn << 4) + (lane & 15);
        const float bv = b2f(b1[n]);
        #pragma unroll
        for (int r = 0; r < 4; ++r) {
            float v = acc[tn][r] + bv;
            v = 0.5f * v * (1.f + erff(v * 0.70710678118654752f));
            Gs[(wv << 4) + rbase + r][n] = f2b(v);
        }
    }
    __syncthreads();
    f32x4 acc2[4] = {};
    #pragma unroll
    for (int k0 = 0; k0 < 64; k0 += 32) {
        const frag8 af = *(const frag8*)(&Gs[mr][k8 + k0]);
        #pragma unroll
        for (int tn = 0; tn < 4; ++tn) {
            const frag8 bfv = *(const frag8*)(&W2s[(tn << 4) + (lane & 15)][k8 + k0]);
            acc2[tn] = __builtin_amdgcn_mfma_f32_16x16x32_bf16(af, bfv, acc2[tn], 0, 0, 0);
        }
    }
    #pragma unroll
    for (int tn = 0; tn < 4; ++tn) {
        const int n = (tn << 4) + (lane & 15);
        const float bv = b2f(b2[n]);
        #pragma unroll
        for (int r = 0; r < 4; ++r) {
            const ll m = m0 + (wv << 4) + rbase + r;
            out[m * 64 + n] = f2b(acc2[tn][r] + bv + b2f(res[m * 64 + n]));
        }
    }
}

// ---- unfold 3x3 s2 p1, token-major [Hin*Hin,64] -> [Ho*Ho,576] (+opt LN) ----
// 4 tokens per 256-thr block; blockIdx.y batches via explicit strides.
__global__ __launch_bounds__(256) void k_unfold576(
    const bf16* __restrict__ in, const int Hin, const int Ho,
    const bf16* __restrict__ g, const bf16* __restrict__ bb,
    const int do_ln, bf16* __restrict__ A,
    const ll inBStride, const ll outBStride)
{
    in += (ll)blockIdx.y * inBStride;
    A  += (ll)blockIdx.y * outBStride;
    const int t = blockIdx.x * 4 + (threadIdx.x >> 6);
    const int l = threadIdx.x & 63;
    const int ho = t / Ho, wo = t - ho * Ho;
    float vals[9];
    float s = 0.f;
    #pragma unroll
    for (int r = 0; r < 9; ++r) {
        const int d = l + (r << 6);
        const int c = d / 9;
        const int rr = d - c * 9;
        const int i = rr / 3, j = rr - i * 3;
        const int hh = 2 * ho + i - 1, ww = 2 * wo + j - 1;
        float val = 0.f;
        if (hh >= 0 && hh < Hin && ww >= 0 && ww < Hin)
            val = b2f(in[((ll)hh * Hin + ww) * 64 + c]);
        vals[r] = val; s += val;
    }
    bf16* out = A + (ll)t * 576;
    if (do_ln) {
        #pragma unroll
        for (int o = 32; o > 0; o >>= 1) s += __shfl_xor(s, o, 64);
        const float mean = s * (1.f / 576.f);
        float s2 = 0.f;
        #pragma unroll
        for (int r = 0; r < 9; ++r) { const float dd = vals[r] - mean; s2 += dd * dd; }
        #pragma unroll
        for (int o = 32; o > 0; o >>= 1) s2 += __shfl_xor(s2, o, 64);
        const float rs = rsqrtf(s2 * (1.f / 576.f) + LN_EPS);
        #pragma unroll
        for (int r = 0; r < 9; ++r) {
            const int d = l + (r << 6);
            out[d] = f2b((vals[r] - mean) * rs * b2f(g[d]) + b2f(bb[d]));
        }
    } else {
        #pragma unroll
        for (int r = 0; r < 9; ++r) out[l + (r << 6)] = f2b(vals[r]);
    }
}

// ---- MFMA bf16 GEMM (unchanged, proven): C[M,N] = A@W^T + bias (+res) ----
__global__ __launch_bounds__(256) void k_gemm(
    const bf16* __restrict__ A, const int lda,
    const bf16* __restrict__ W,
    const bf16* __restrict__ bias,
    const bf16* res, const int ldres,
    void* C, const int ldc, const ll mOff,
    const int K, const int* outm)
{
    __shared__ bf16 As[64][40];
    __shared__ bf16 Bs[64][40];
    const int tid = threadIdx.x;
    const int wv = tid >> 6;
    const int lane = tid & 63;
    const ll m0 = (ll)blockIdx.x * 64;
    const int n0 = blockIdx.y * 64;
    f32x4 acc[4] = {};
    const int lr = tid >> 2;
    const int lc = (tid & 3) << 3;
    const int mr = (wv << 4) + (lane & 15);
    const int k8 = (lane >> 4) << 3;
    const bf16* Ag = A + (m0 + lr) * (ll)lda + lc;
    const bf16* Wg = W + (ll)(n0 + lr) * K + lc;
    for (int k0 = 0; k0 < K; k0 += 32) {
        const uint4 av = *(const uint4*)(Ag + k0);
        *(uint4*)(&As[lr][lc]) = av;
        const uint4 wv4 = *(const uint4*)(Wg + k0);
        *(uint4*)(&Bs[lr][lc]) = wv4;
        __syncthreads();
        const frag8 af = *(const frag8*)(&As[mr][k8]);
        #pragma unroll
        for (int tn = 0; tn < 4; ++tn) {
            const frag8 bfv = *(const frag8*)(&Bs[(tn << 4) + (lane & 15)][k8]);
            acc[tn] = __builtin_amdgcn_mfma_f32_16x16x32_bf16(af, bfv, acc[tn], 0, 0, 0);
        }
        __syncthreads();
    }
    const int om = outm ? *outm : 0;
    const int rbase = (lane >> 4) << 2;
    #pragma unroll
    for (int tn = 0; tn < 4; ++tn) {
        const int n = n0 + (tn << 4) + (lane & 15);
        const float bv = bias ? b2f(bias[n]) : 0.f;
        #pragma unroll
        for (int r = 0; r < 4; ++r) {
            const ll m = m0 + (wv << 4) + rbase + r;
            float v = acc[tn][r] + bv;
            if (res) v += b2f(res[m * (ll)ldres + n]);
            const ll ci = (m + mOff) * (ll)ldc + n;
            if (om) ((float*)C)[ci] = v;
            else    ((bf16*)C)[ci] = f2b(v);
        }
    }
}

// ---- fused prm_exp for stage-2 (k and q in one pass) + RED zeroing ----
__global__ __launch_bounds__(256) void k_fusedP2(
    const bf16* __restrict__ kqv, const bf16* __restrict__ pw,
    bf16* __restrict__ KP, bf16* __restrict__ QP,
    float* __restrict__ redBase, const int T)
{
    __shared__ float wps[2048];
    const int tid = threadIdx.x;
    const int bz = blockIdx.y;
    for (int i = tid; i < 2048; i += 256) wps[i] = b2f(pw[i]);
    if (blockIdx.x == 0) {
        float* red = redBase + (ll)bz * 2080;
        for (int i = tid; i < 2080; i += 256) red[i] = 0.f;
    }
    __syncthreads();
    const ll gt = (ll)bz * T + blockIdx.x * 256 + tid;
    const bf16* row = kqv + gt * 192;
    float xv[64];
    float xd = 0.f;
    #pragma unroll
    for (int e = 0; e < 64; ++e) { xv[e] = b2f(row[e]); xd += xv[e] * xv[e]; }
    xd *= 0.5f;
    #pragma unroll 4
    for (int m = 0; m < 32; ++m) {
        float a = -xd;
        #pragma unroll
        for (int e = 0; e < 64; ++e) a += xv[e] * wps[m * 64 + e];
        KP[gt * 32 + m] = f2b(expf(fminf(a, 30.f)) * INV_SQRT_M);
    }
    xd = 0.f;
    #pragma unroll
    for (int e = 0; e < 64; ++e) { xv[e] = b2f(row[64 + e]); xd += xv[e] * xv[e]; }
    xd *= 0.5f;
    #pragma unroll 4
    for (int m = 0; m < 32; ++m) {
        float a = -xd;
        #pragma unroll
        for (int e = 0; e < 64; ++e) a += xv[e] * wps[m * 64 + e];
        QP[gt * 32 + m] = f2b(expf(fminf(a, 30.f)) * INV_SQRT_M);
    }
}

extern "C" void kernel_launch(void* const* d_in, const int* in_sizes, int n_in,
                              void* d_out, int out_size, void* d_ws, size_t ws_size,
                              hipStream_t stream)
{
    (void)in_sizes; (void)n_in; (void)out_size; (void)ws_size;
    const int T1 = 50176, T2 = 12544;
    char* ws = (char*)d_ws;

    // ---- cursor-based workspace allocation (peak 24,517,888 B <= known-safe) ----
    size_t cur = 0;
    auto alloc = [&](size_t bytes) {
        size_t r = cur; cur += (bytes + 127) & ~(size_t)127; return r;
    };
    static const int segIdx[28] = {0, 2, 3, 4, 5, 6, 7, 8, 9, 10, 11, 12, 13,
                                   14, 15, 16, 17, 18, 19, 20, 21, 22, 23, 24, 25, 26, 27, 28};
    static const int segN[28] = {1204224, 192, 4096, 64, 27, 27, 64, 64, 4096, 64, 4096, 64, 2048,
                                 110592, 192, 4096, 64, 576, 576, 64, 64, 4096, 64, 4096, 64, 2048,
                                 442368, 768};
    size_t segOff[28];
    for (int i = 0; i < 28; ++i) segOff[i] = alloc((size_t)segN[i] * 2);
    const size_t oMODE = alloc(256);
    const size_t oRED  = alloc(66560);             // 8 x 2080 fp32
    const size_t oBIG  = alloc(6422528);           // [T1,64]
    const size_t oKP   = alloc(3211264);           // [T1,32]
    const size_t oQP   = alloc(3211264);           // [T1,32]
    (void)oQP;

    // named param pointers (order matches segIdx)
    bf16* P[28];
    for (int i = 0; i < 28; ++i) P[i] = (bf16*)(ws + segOff[i]);
    bf16* XC = P[0];
    bf16 *P1KQVB = P[1], *P1PW = P[2], *P1PB = P[3], *P1N1G = P[4], *P1N1B = P[5];
    bf16 *P1N2G = P[6], *P1N2B = P[7], *P1M1W = P[8], *P1M1B = P[9], *P1M2W = P[10];
    bf16 *P1M2B = P[11], *P1W = P[12];
    bf16 *P2KQVW = P[13], *P2KQVB = P[14], *P2PW = P[15], *P2PB = P[16];
    bf16 *P2N1G = P[17], *P2N1B = P[18], *P2N2G = P[19], *P2N2B = P[20];
    bf16 *P2M1W = P[21], *P2M1B = P[22], *P2M2W = P[23], *P2M2B = P[24], *P2W = P[25];
    bf16 *PROJW = P[26], *PROJB = P[27];

    int*   MODE = (int*)(ws + oMODE);
    float* REDF = (float*)(ws + oRED);
    bf16*  BIG  = (bf16*)(ws + oBIG);              // stage-1 V/Y/OUT (in-place chain)
    bf16*  KP   = (bf16*)(ws + oKP);
    bf16*  QP   = (bf16*)(ws + oKP + 3211264);
    bf16*  A2   = (bf16*)(ws + oKP);               // [T2,576] over dead KP/QP (14,450,688 B)
    // batched-tail aliases
    bf16*  KQV2F = (bf16*)d_out;                   // [8*T2,192] = 38,535,168 B scratch in d_out
    bf16*  KP2F  = (bf16*)(ws + oKP);              // [8*T2,32]
    bf16*  QP2F  = (bf16*)(ws + oKP + 6422528);    // [8*T2,32]
    bf16*  YB2F  = (bf16*)(ws + oBIG);             // [8*T2,64] = 12,845,056 B (over BIG, dead)
    bf16*  A3c   = (bf16*)(ws + oBIG + 12845056);  // [6272,576] chunk = 7,225,344 B

    // ---- prologue: sniff dtype, convert all inputs to bf16 in ws ----
    k_sniff<<<1, 256, 0, stream>>>(d_in[0], MODE);
    CvTab tab;
    int cum = 0;
    for (int i = 0; i < 28; ++i) {
        tab.src[i] = d_in[segIdx[i]];
        tab.dstOff[i] = (int)(segOff[i] / 2);
        tab.cum[i] = cum;
        cum += segN[i];
    }
    tab.cum[28] = cum;
    k_convert_all<<<(cum + 255) / 256, 256, 0, stream>>>(tab, (bf16*)ws, MODE);

    // ---- per-batch: stage 1 + stage-2 front (unfold + kqv GEMM into d_out) ----
    for (int b = 0; b < 8; ++b) {
        float* REDb = REDF + (ll)b * 2080;
        k_fused1<<<196, 256, 0, stream>>>(XC, d_in[1], P1KQVB, P1N1G, P1N1B, P1W,
                                          MODE, KP, QP, BIG, REDb, b);
        k_reduce<<<dim3(196, 1), 256, 0, stream>>>(KP, BIG, 64, T1, REDb, 256);
        k_posta<<<dim3(196, 1), 256, 0, stream>>>(QP, REDb, BIG, 64, P1PW, P1PB,
                                                  BIG, T1);
        k_mlpln<<<784, 256, 0, stream>>>(BIG, P1N2G, P1N2B, P1M1W, P1M1B,
                                         P1M2W, P1M2B, BIG, BIG);
        k_unfold576<<<dim3(3136, 1), 256, 0, stream>>>(BIG, 224, 112, P2N1G, P2N1B,
                                                       1, A2, 0, 0);
        k_gemm<<<dim3(196, 3), 256, 0, stream>>>(A2, 576, P2KQVW, P2KQVB,
            nullptr, 0, KQV2F, 192, (ll)b * T2, 576, nullptr);
    }

    // ---- batched stage-2 tail (all 8 batches, full occupancy) ----
    k_fusedP2<<<dim3(49, 8), 256, 0, stream>>>(KQV2F, P2W, KP2F, QP2F, REDF, T2);
    k_reduce<<<dim3(49, 8), 256, 0, stream>>>(KP2F, KQV2F + 128, 192, T2, REDF, 256);
    k_posta<<<dim3(49, 8), 256, 0, stream>>>(QP2F, REDF, KQV2F + 128, 192,
                                             P2PW, P2PB, YB2F, T2);
    k_mlpln<<<1568, 256, 0, stream>>>(YB2F, P2N2G, P2N2B, P2M1W, P2M1B,
                                      P2M2W, P2M2B, YB2F, YB2F);

    // ---- epilogue: stage-3 unfold + final projection (KQV2F scratch now dead) ----
    for (int c = 0; c < 4; ++c) {
        k_unfold576<<<dim3(784, 2), 256, 0, stream>>>(
            YB2F + (ll)(2 * c) * T2 * 64, 112, 56, nullptr, nullptr, 0,
            A3c, (ll)T2 * 64, (ll)3136 * 576);
        k_gemm<<<dim3(98, 12), 256, 0, stream>>>(A3c, 576, PROJW, PROJB,
            nullptr, 0, d_out, 768, (ll)c * 6272, 576, MODE);
    }
}

// Round 6
// 2053.884 us; speedup vs baseline: 2.5301x; 1.0748x over previous
//
#include <hip/hip_runtime.h>
#include <hip/hip_bf16.h>
#include <math.h>

typedef __hip_bfloat16 bf16;
typedef __attribute__((ext_vector_type(8))) short frag8;
typedef __attribute__((ext_vector_type(4))) float f32x4;
typedef long long ll;

__device__ __forceinline__ float b2f(bf16 v) { return __bfloat162float(v); }
__device__ __forceinline__ bf16 f2b(float v) { return __float2bfloat16(v); }

// pack two floats into one dword of bf16x2
__device__ __forceinline__ unsigned pk2f(float a, float b) {
    union { bf16 h[2]; unsigned u; } c;
    c.h[0] = f2b(a); c.h[1] = f2b(b);
    return c.u;
}
// unpack 8 consecutive bf16 (16B-aligned) into floats
__device__ __forceinline__ void up8(const bf16* p, float* f) {
    const uint4 u = *(const uint4*)p;
    union { unsigned u; bf16 h[2]; } c;
    c.u = u.x; f[0] = b2f(c.h[0]); f[1] = b2f(c.h[1]);
    c.u = u.y; f[2] = b2f(c.h[0]); f[3] = b2f(c.h[1]);
    c.u = u.z; f[4] = b2f(c.h[0]); f[5] = b2f(c.h[1]);
    c.u = u.w; f[6] = b2f(c.h[0]); f[7] = b2f(c.h[1]);
}

#define LN_EPS 1e-5f
#define D_EPS 1e-8f
#define INV_SQRT_M 0.17677669529663687f

// ---------------- dtype sniffer: mode=1 if d_in[0] is float32, 0 if bf16 -------------
__global__ __launch_bounds__(256) void k_sniff(const void* x, int* mode)
{
    __shared__ int cnt;
    if (threadIdx.x == 0) cnt = 0;
    __syncthreads();
    const unsigned short* u = (const unsigned short*)x;
    const unsigned short h = u[2 * threadIdx.x];
    const unsigned int bits = ((unsigned int)h) << 16;
    const float v = __uint_as_float(bits);
    const float a = fabsf(v);
    const bool sane = (h == 0) || (a >= 1e-8f && a <= 1e4f);
    if (!sane) atomicAdd(&cnt, 1);
    __syncthreads();
    if (threadIdx.x == 0) *mode = (cnt > 64) ? 1 : 0;
}

// ---------------- single table-driven convert of all params + x ----------------
struct CvTab { const void* src[28]; int dstOff[28]; int cum[29]; };

__global__ __launch_bounds__(256) void k_convert_all(CvTab tab, bf16* base,
                                                     const int* mode)
{
    const int idx = blockIdx.x * 256 + threadIdx.x;
    if (idx >= tab.cum[28]) return;
    int s = 0;
    while (idx >= tab.cum[s + 1]) ++s;
    const int local = idx - tab.cum[s];
    const float v = (*mode) ? ((const float*)tab.src[s])[local]
                            : b2f(((const bf16*)tab.src[s])[local]);
    base[tab.dstOff[s] + local] = f2b(v);
}

// ---- fused stage-1 front: unfold27 + LN(27) + kqv + prm_exp(k,q) ----
__global__ __launch_bounds__(256) void k_fused1(
    const bf16* __restrict__ x, const void* __restrict__ w1raw,
    const bf16* __restrict__ kqvb, const bf16* __restrict__ n1g,
    const bf16* __restrict__ n1b, const bf16* __restrict__ pw,
    const int* __restrict__ mode,
    bf16* __restrict__ KP, bf16* __restrict__ QP, bf16* __restrict__ V,
    float* __restrict__ red, const int b)
{
    __shared__ float w1s[5184];   // [192][27]
    __shared__ float wps[2048];   // [32][64]
    __shared__ float kbs[192];
    __shared__ float gs[27], bs[27];
    const int tid = threadIdx.x;
    const int md = *mode;
    for (int i = tid; i < 5184; i += 256)
        w1s[i] = md ? ((const float*)w1raw)[i] : b2f(((const bf16*)w1raw)[i]);
    for (int i = tid; i < 2048; i += 256) wps[i] = b2f(pw[i]);
    if (tid < 192) kbs[tid] = b2f(kqvb[tid]);
    if (tid < 27) { gs[tid] = b2f(n1g[tid]); bs[tid] = b2f(n1b[tid]); }
    if (blockIdx.x == 0)
        for (int i = tid; i < 2080; i += 256) red[i] = 0.f;
    __syncthreads();

    const int t = blockIdx.x * 256 + tid;          // < 50176
    const int h = t / 224, w = t - h * 224;
    float tv[27];
    #pragma unroll
    for (int c = 0; c < 3; ++c)
        #pragma unroll
        for (int i = 0; i < 3; ++i)
            #pragma unroll
            for (int j = 0; j < 3; ++j) {
                const int hh = h + i - 1, ww = w + j - 1;
                float val = 0.f;
                if (hh >= 0 && hh < 224 && ww >= 0 && ww < 224)
                    val = b2f(x[((ll)(b * 3 + c) * 224 + hh) * 224 + ww]);
                tv[c * 9 + i * 3 + j] = val;
            }
    float s = 0.f;
    #pragma unroll
    for (int d = 0; d < 27; ++d) s += tv[d];
    const float mean = s * (1.f / 27.f);
    float s2 = 0.f;
    #pragma unroll
    for (int d = 0; d < 27; ++d) { const float dd = tv[d] - mean; s2 += dd * dd; }
    const float rs = rsqrtf(s2 * (1.f / 27.f) + LN_EPS);
    #pragma unroll
    for (int d = 0; d < 27; ++d) tv[d] = (tv[d] - mean) * rs * gs[d] + bs[d];

    float t64[64];
    float p32[32];
    // ---- K -> KP ----
    #pragma unroll
    for (int o = 0; o < 64; ++o) {
        float a = kbs[o];
        #pragma unroll
        for (int d = 0; d < 27; ++d) a += tv[d] * w1s[o * 27 + d];
        t64[o] = a;
    }
    float xd = 0.f;
    #pragma unroll
    for (int e = 0; e < 64; ++e) xd += t64[e] * t64[e];
    xd *= 0.5f;
    #pragma unroll 4
    for (int m = 0; m < 32; ++m) {
        float a = -xd;
        #pragma unroll
        for (int e = 0; e < 64; ++e) a += t64[e] * wps[m * 64 + e];
        p32[m] = expf(fminf(a, 30.f)) * INV_SQRT_M;
    }
    #pragma unroll
    for (int g = 0; g < 4; ++g) {
        uint4 st;
        st.x = pk2f(p32[g * 8 + 0], p32[g * 8 + 1]);
        st.y = pk2f(p32[g * 8 + 2], p32[g * 8 + 3]);
        st.z = pk2f(p32[g * 8 + 4], p32[g * 8 + 5]);
        st.w = pk2f(p32[g * 8 + 6], p32[g * 8 + 7]);
        *(uint4*)(KP + (ll)t * 32 + g * 8) = st;
    }
    // ---- Q -> QP ----
    #pragma unroll
    for (int o = 0; o < 64; ++o) {
        float a = kbs[64 + o];
        #pragma unroll
        for (int d = 0; d < 27; ++d) a += tv[d] * w1s[(64 + o) * 27 + d];
        t64[o] = a;
    }
    xd = 0.f;
    #pragma unroll
    for (int e = 0; e < 64; ++e) xd += t64[e] * t64[e];
    xd *= 0.5f;
    #pragma unroll 4
    for (int m = 0; m < 32; ++m) {
        float a = -xd;
        #pragma unroll
        for (int e = 0; e < 64; ++e) a += t64[e] * wps[m * 64 + e];
        p32[m] = expf(fminf(a, 30.f)) * INV_SQRT_M;
    }
    #pragma unroll
    for (int g = 0; g < 4; ++g) {
        uint4 st;
        st.x = pk2f(p32[g * 8 + 0], p32[g * 8 + 1]);
        st.y = pk2f(p32[g * 8 + 2], p32[g * 8 + 3]);
        st.z = pk2f(p32[g * 8 + 4], p32[g * 8 + 5]);
        st.w = pk2f(p32[g * 8 + 6], p32[g * 8 + 7]);
        *(uint4*)(QP + (ll)t * 32 + g * 8) = st;
    }
    // ---- V ----
    #pragma unroll
    for (int g = 0; g < 8; ++g) {
        float o8[8];
        #pragma unroll
        for (int k = 0; k < 8; ++k) {
            const int o = g * 8 + k;
            float a = kbs[128 + o];
            #pragma unroll
            for (int d = 0; d < 27; ++d) a += tv[d] * w1s[(128 + o) * 27 + d];
            o8[k] = a;
        }
        uint4 st;
        st.x = pk2f(o8[0], o8[1]); st.y = pk2f(o8[2], o8[3]);
        st.z = pk2f(o8[4], o8[5]); st.w = pk2f(o8[6], o8[7]);
        *(uint4*)(V + (ll)t * 64 + g * 8) = st;
    }
}

// ---- reduce over tokens (batched via blockIdx.y) ----
__global__ __launch_bounds__(256) void k_reduce(
    const bf16* __restrict__ kpB, const bf16* __restrict__ vB, const int vstride,
    const int T, float* __restrict__ redBase, const int chunk)
{
    __shared__ float kps[64][33];
    __shared__ float vs[64][65];
    const int bz = blockIdx.y;
    const bf16* kp = kpB + (ll)bz * T * 32;
    const bf16* v  = vB + (ll)bz * T * (ll)vstride;
    float* red = redBase + (ll)bz * 2080;
    const int tid = threadIdx.x;
    const int m = tid & 31, n8 = tid >> 5;
    float acc[8] = {0.f, 0.f, 0.f, 0.f, 0.f, 0.f, 0.f, 0.f};
    float ksum = 0.f;
    const int t0 = blockIdx.x * chunk;
    for (int tt = 0; tt < chunk; tt += 64) {
        __syncthreads();
        #pragma unroll
        for (int i = 0; i < 8; ++i) {
            const int li = tid + i * 256;
            const int tok = li >> 5, mm = li & 31;
            const int gt = t0 + tt + tok;
            kps[tok][mm] = (gt < T) ? b2f(kp[(ll)gt * 32 + mm]) : 0.f;
        }
        #pragma unroll
        for (int i = 0; i < 16; ++i) {
            const int li = tid + i * 256;
            const int tok = li >> 6, nn = li & 63;
            const int gt = t0 + tt + tok;
            vs[tok][nn] = (gt < T) ? b2f(v[(ll)gt * vstride + nn]) : 0.f;
        }
        __syncthreads();
        #pragma unroll 8
        for (int tok = 0; tok < 64; ++tok) {
            const float kv = kps[tok][m];
            ksum += kv;
            #pragma unroll
            for (int r = 0; r < 8; ++r)
                acc[r] += vs[tok][n8 * 8 + r] * kv;
        }
    }
    #pragma unroll
    for (int r = 0; r < 8; ++r)
        atomicAdd(&red[(n8 * 8 + r) * 32 + m], acc[r]);
    if (n8 == 0) atomicAdd(&red[2048 + m], ksum);
}

// ---- fused post-attention: y0 = qp@kptv^T, /(D+eps), @pw^T + pb + v ----
__global__ __launch_bounds__(256) void k_posta(
    const bf16* __restrict__ qpB, const float* __restrict__ redBase,
    const bf16* vB, const int vstride,
    const bf16* __restrict__ pw, const bf16* __restrict__ pb,
    bf16* outB, const int T)
{
    __shared__ float kpt[2080];
    __shared__ float pws[4096];
    __shared__ float pbs[64];
    const int tid = threadIdx.x;
    const int bz = blockIdx.y;
    const float* red = redBase + (ll)bz * 2080;
    const bf16* qp = qpB + (ll)bz * T * 32;
    const bf16* v  = vB + (ll)bz * T * (ll)vstride;
    bf16* out = outB + (ll)bz * T * 64;
    for (int i = tid; i < 2080; i += 256) kpt[i] = red[i];
    for (int i = tid; i < 4096; i += 256) pws[i] = b2f(pw[i]);
    if (tid < 64) pbs[tid] = b2f(pb[tid]);
    __syncthreads();
    const int t = blockIdx.x * 256 + tid;
    float q[32];
    up8(qp + (ll)t * 32, q);
    up8(qp + (ll)t * 32 + 8, q + 8);
    up8(qp + (ll)t * 32 + 16, q + 16);
    up8(qp + (ll)t * 32 + 24, q + 24);
    float D = D_EPS;
    #pragma unroll
    for (int m = 0; m < 32; ++m) D += q[m] * kpt[2048 + m];
    const float inv = 1.f / D;
    float y0[64];
    #pragma unroll
    for (int n = 0; n < 64; ++n) {
        float a = 0.f;
        #pragma unroll
        for (int m = 0; m < 32; ++m) a += q[m] * kpt[n * 32 + m];
        y0[n] = a * inv;
    }
    #pragma unroll
    for (int g = 0; g < 8; ++g) {
        float o8[8];
        #pragma unroll
        for (int k = 0; k < 8; ++k) {
            const int n = g * 8 + k;
            float a = pbs[n];
            #pragma unroll
            for (int j = 0; j < 64; ++j) a += y0[j] * pws[n * 64 + j];
            o8[k] = a;
        }
        float vv[8];
        up8(v + (ll)t * vstride + g * 8, vv);
        uint4 st;
        st.x = pk2f(o8[0] + vv[0], o8[1] + vv[1]);
        st.y = pk2f(o8[2] + vv[2], o8[3] + vv[3]);
        st.z = pk2f(o8[4] + vv[4], o8[5] + vv[5]);
        st.w = pk2f(o8[6] + vv[6], o8[7] + vv[7]);
        *(uint4*)(out + (ll)t * 64 + g * 8) = st;
    }
}

// ---- fused LN(64) + MLP (MFMA): out = res + gelu(LN(H)@w1^T+b1)@w2^T+b2 ----
__global__ __launch_bounds__(256) void k_mlpln(
    const bf16* H, const bf16* __restrict__ n2g, const bf16* __restrict__ n2b,
    const bf16* __restrict__ w1, const bf16* __restrict__ b1,
    const bf16* __restrict__ w2, const bf16* __restrict__ b2,
    const bf16* res, bf16* out)
{
    __shared__ bf16 Hs[64][72];
    __shared__ bf16 W1s[64][72];
    __shared__ bf16 W2s[64][72];
    __shared__ bf16 Gs[64][72];
    __shared__ float mns[64], rss[64];
    const int tid = threadIdx.x;
    const int wv = tid >> 6, lane = tid & 63;
    const ll m0 = (ll)blockIdx.x * 64;
    const int lr = tid >> 2;
    const int lc = (tid & 3) << 4;
    *(uint4*)(&Hs[lr][lc])      = *(const uint4*)(H + (m0 + lr) * 64 + lc);
    *(uint4*)(&Hs[lr][lc + 8])  = *(const uint4*)(H + (m0 + lr) * 64 + lc + 8);
    *(uint4*)(&W1s[lr][lc])     = *(const uint4*)(w1 + lr * 64 + lc);
    *(uint4*)(&W1s[lr][lc + 8]) = *(const uint4*)(w1 + lr * 64 + lc + 8);
    *(uint4*)(&W2s[lr][lc])     = *(const uint4*)(w2 + lr * 64 + lc);
    *(uint4*)(&W2s[lr][lc + 8]) = *(const uint4*)(w2 + lr * 64 + lc + 8);
    __syncthreads();
    if (tid < 64) {
        float s = 0.f, s2 = 0.f;
        #pragma unroll
        for (int n = 0; n < 64; ++n) { const float vv = b2f(Hs[tid][n]); s += vv; s2 += vv * vv; }
        const float mn = s * (1.f / 64.f);
        const float var = fmaxf(s2 * (1.f / 64.f) - mn * mn, 0.f);
        mns[tid] = mn; rss[tid] = rsqrtf(var + LN_EPS);
    }
    __syncthreads();
    for (int i = tid; i < 4096; i += 256) {
        const int r = i >> 6, c = i & 63;
        Hs[r][c] = f2b((b2f(Hs[r][c]) - mns[r]) * rss[r] * b2f(n2g[c]) + b2f(n2b[c]));
    }
    __syncthreads();
    const int mr = (wv << 4) + (lane & 15);
    const int k8 = (lane >> 4) << 3;
    const int rbase = (lane >> 4) << 2;
    f32x4 acc[4] = {};
    #pragma unroll
    for (int k0 = 0; k0 < 64; k0 += 32) {
        const frag8 af = *(const frag8*)(&Hs[mr][k8 + k0]);
        #pragma unroll
        for (int tn = 0; tn < 4; ++tn) {
            const frag8 bfv = *(const frag8*)(&W1s[(tn << 4) + (lane & 15)][k8 + k0]);
            acc[tn] = __builtin_amdgcn_mfma_f32_16x16x32_bf16(af, bfv, acc[tn], 0, 0, 0);
        }
    }
    #pragma unroll
    for (int tn = 0; tn < 4; ++tn) {
        const int n = (tn << 4) + (lane & 15);
        const float bv = b2f(b1[n]);
        #pragma unroll
        for (int r = 0; r < 4; ++r) {
            float v = acc[tn][r] + bv;
            v = 0.5f * v * (1.f + erff(v * 0.70710678118654752f));
            Gs[(wv << 4) + rbase + r][n] = f2b(v);
        }
    }
    __syncthreads();
    f32x4 acc2[4] = {};
    #pragma unroll
    for (int k0 = 0; k0 < 64; k0 += 32) {
        const frag8 af = *(const frag8*)(&Gs[mr][k8 + k0]);
        #pragma unroll
        for (int tn = 0; tn < 4; ++tn) {
            const frag8 bfv = *(const frag8*)(&W2s[(tn << 4) + (lane & 15)][k8 + k0]);
            acc2[tn] = __builtin_amdgcn_mfma_f32_16x16x32_bf16(af, bfv, acc2[tn], 0, 0, 0);
        }
    }
    // stage epilogue sums into Hs (dead), then coalesced vector stores + vector res add
    #pragma unroll
    for (int tn = 0; tn < 4; ++tn) {
        const int n = (tn << 4) + (lane & 15);
        const float bv = b2f(b2[n]);
        #pragma unroll
        for (int r = 0; r < 4; ++r)
            Hs[(wv << 4) + rbase + r][n] = f2b(acc2[tn][r] + bv);
    }
    __syncthreads();
    const int row = tid >> 2;
    const int colg = (tid & 3) << 4;
    const bf16* rsrc = res + (m0 + row) * 64 + colg;
    bf16* dst = out + (m0 + row) * 64 + colg;
    #pragma unroll
    for (int hh = 0; hh < 2; ++hh) {
        float sv[8], rv[8];
        up8(&Hs[row][colg + hh * 8], sv);
        up8(rsrc + hh * 8, rv);
        uint4 st;
        st.x = pk2f(sv[0] + rv[0], sv[1] + rv[1]);
        st.y = pk2f(sv[2] + rv[2], sv[3] + rv[3]);
        st.z = pk2f(sv[4] + rv[4], sv[5] + rv[5]);
        st.w = pk2f(sv[6] + rv[6], sv[7] + rv[7]);
        *(uint4*)(dst + hh * 8) = st;
    }
}

// ---- unfold 3x3 s2 p1, token-major [Hin*Hin,64] -> [Ho*Ho,576] (+opt LN) ----
__global__ __launch_bounds__(256) void k_unfold576(
    const bf16* __restrict__ in, const int Hin, const int Ho,
    const bf16* __restrict__ g, const bf16* __restrict__ bb,
    const int do_ln, bf16* __restrict__ A,
    const ll inBStride, const ll outBStride)
{
    in += (ll)blockIdx.y * inBStride;
    A  += (ll)blockIdx.y * outBStride;
    const int t = blockIdx.x * 4 + (threadIdx.x >> 6);
    const int l = threadIdx.x & 63;
    const int ho = t / Ho, wo = t - ho * Ho;
    float vals[9];
    float s = 0.f;
    #pragma unroll
    for (int r = 0; r < 9; ++r) {
        const int d = l + (r << 6);
        const int c = d / 9;
        const int rr = d - c * 9;
        const int i = rr / 3, j = rr - i * 3;
        const int hh = 2 * ho + i - 1, ww = 2 * wo + j - 1;
        float val = 0.f;
        if (hh >= 0 && hh < Hin && ww >= 0 && ww < Hin)
            val = b2f(in[((ll)hh * Hin + ww) * 64 + c]);
        vals[r] = val; s += val;
    }
    bf16* out = A + (ll)t * 576;
    if (do_ln) {
        #pragma unroll
        for (int o = 32; o > 0; o >>= 1) s += __shfl_xor(s, o, 64);
        const float mean = s * (1.f / 576.f);
        float s2 = 0.f;
        #pragma unroll
        for (int r = 0; r < 9; ++r) { const float dd = vals[r] - mean; s2 += dd * dd; }
        #pragma unroll
        for (int o = 32; o > 0; o >>= 1) s2 += __shfl_xor(s2, o, 64);
        const float rs = rsqrtf(s2 * (1.f / 576.f) + LN_EPS);
        #pragma unroll
        for (int r = 0; r < 9; ++r) {
            const int d = l + (r << 6);
            out[d] = f2b((vals[r] - mean) * rs * b2f(g[d]) + b2f(bb[d]));
        }
    } else {
        #pragma unroll
        for (int r = 0; r < 9; ++r) out[l + (r << 6)] = f2b(vals[r]);
    }
}

// ---- MFMA bf16 GEMM: C[M,N] = A@W^T + bias (+res); coalesced LDS-staged epilogue ----
__global__ __launch_bounds__(256) void k_gemm(
    const bf16* __restrict__ A, const int lda,
    const bf16* __restrict__ W,
    const bf16* __restrict__ bias,
    const bf16* res, const int ldres,
    void* C, const int ldc, const ll mOff,
    const int K, const int* outm)
{
    __shared__ bf16 As[64][40];
    __shared__ bf16 Bs[64][40];
    __shared__ bf16 Cs[64][72];
    const int tid = threadIdx.x;
    const int wv = tid >> 6;
    const int lane = tid & 63;
    const ll m0 = (ll)blockIdx.x * 64;
    const int n0 = blockIdx.y * 64;
    f32x4 acc[4] = {};
    const int lr = tid >> 2;
    const int lc = (tid & 3) << 3;
    const int mr = (wv << 4) + (lane & 15);
    const int k8 = (lane >> 4) << 3;
    const bf16* Ag = A + (m0 + lr) * (ll)lda + lc;
    const bf16* Wg = W + (ll)(n0 + lr) * K + lc;
    for (int k0 = 0; k0 < K; k0 += 32) {
        const uint4 av = *(const uint4*)(Ag + k0);
        *(uint4*)(&As[lr][lc]) = av;
        const uint4 wv4 = *(const uint4*)(Wg + k0);
        *(uint4*)(&Bs[lr][lc]) = wv4;
        __syncthreads();
        const frag8 af = *(const frag8*)(&As[mr][k8]);
        #pragma unroll
        for (int tn = 0; tn < 4; ++tn) {
            const frag8 bfv = *(const frag8*)(&Bs[(tn << 4) + (lane & 15)][k8]);
            acc[tn] = __builtin_amdgcn_mfma_f32_16x16x32_bf16(af, bfv, acc[tn], 0, 0, 0);
        }
        __syncthreads();
    }
    const int om = outm ? *outm : 0;
    const int rbase = (lane >> 4) << 2;
    if (om) {   // fp32 output path (final proj when inputs are fp32)
        #pragma unroll
        for (int tn = 0; tn < 4; ++tn) {
            const int n = n0 + (tn << 4) + (lane & 15);
            const float bv = bias ? b2f(bias[n]) : 0.f;
            #pragma unroll
            for (int r = 0; r < 4; ++r) {
                const ll m = m0 + (wv << 4) + rbase + r;
                float v = acc[tn][r] + bv;
                if (res) v += b2f(res[m * (ll)ldres + n]);
                ((float*)C)[(m + mOff) * (ll)ldc + n] = v;
            }
        }
        return;
    }
    #pragma unroll
    for (int tn = 0; tn < 4; ++tn) {
        const int nl = (tn << 4) + (lane & 15);
        const float bv = bias ? b2f(bias[n0 + nl]) : 0.f;
        #pragma unroll
        for (int r = 0; r < 4; ++r) {
            const ll m = m0 + (wv << 4) + rbase + r;
            float v = acc[tn][r] + bv;
            if (res) v += b2f(res[m * (ll)ldres + n0 + nl]);
            Cs[(wv << 4) + rbase + r][nl] = f2b(v);
        }
    }
    __syncthreads();
    const int row = tid >> 2;
    const int colg = (tid & 3) << 4;
    bf16* dst = (bf16*)C + (m0 + mOff + row) * (ll)ldc + n0 + colg;
    *(uint4*)dst       = *(const uint4*)(&Cs[row][colg]);
    *(uint4*)(dst + 8) = *(const uint4*)(&Cs[row][colg + 8]);
}

// ---- fused prm_exp for stage-2 (k and q in one pass) + RED zeroing ----
__global__ __launch_bounds__(256) void k_fusedP2(
    const bf16* __restrict__ kqv, const bf16* __restrict__ pw,
    bf16* __restrict__ KP, bf16* __restrict__ QP,
    float* __restrict__ redBase, const int T)
{
    __shared__ float wps[2048];
    const int tid = threadIdx.x;
    const int bz = blockIdx.y;
    for (int i = tid; i < 2048; i += 256) wps[i] = b2f(pw[i]);
    if (blockIdx.x == 0) {
        float* red = redBase + (ll)bz * 2080;
        for (int i = tid; i < 2080; i += 256) red[i] = 0.f;
    }
    __syncthreads();
    const ll gt = (ll)bz * T + blockIdx.x * 256 + tid;
    const bf16* row = kqv + gt * 192;
    float xv[64];
    float p32[32];
    #pragma unroll
    for (int g = 0; g < 8; ++g) up8(row + g * 8, xv + g * 8);
    float xd = 0.f;
    #pragma unroll
    for (int e = 0; e < 64; ++e) xd += xv[e] * xv[e];
    xd *= 0.5f;
    #pragma unroll 4
    for (int m = 0; m < 32; ++m) {
        float a = -xd;
        #pragma unroll
        for (int e = 0; e < 64; ++e) a += xv[e] * wps[m * 64 + e];
        p32[m] = expf(fminf(a, 30.f)) * INV_SQRT_M;
    }
    #pragma unroll
    for (int g = 0; g < 4; ++g) {
        uint4 st;
        st.x = pk2f(p32[g * 8 + 0], p32[g * 8 + 1]);
        st.y = pk2f(p32[g * 8 + 2], p32[g * 8 + 3]);
        st.z = pk2f(p32[g * 8 + 4], p32[g * 8 + 5]);
        st.w = pk2f(p32[g * 8 + 6], p32[g * 8 + 7]);
        *(uint4*)(KP + gt * 32 + g * 8) = st;
    }
    #pragma unroll
    for (int g = 0; g < 8; ++g) up8(row + 64 + g * 8, xv + g * 8);
    xd = 0.f;
    #pragma unroll
    for (int e = 0; e < 64; ++e) xd += xv[e] * xv[e];
    xd *= 0.5f;
    #pragma unroll 4
    for (int m = 0; m < 32; ++m) {
        float a = -xd;
        #pragma unroll
        for (int e = 0; e < 64; ++e) a += xv[e] * wps[m * 64 + e];
        p32[m] = expf(fminf(a, 30.f)) * INV_SQRT_M;
    }
    #pragma unroll
    for (int g = 0; g < 4; ++g) {
        uint4 st;
        st.x = pk2f(p32[g * 8 + 0], p32[g * 8 + 1]);
        st.y = pk2f(p32[g * 8 + 2], p32[g * 8 + 3]);
        st.z = pk2f(p32[g * 8 + 4], p32[g * 8 + 5]);
        st.w = pk2f(p32[g * 8 + 6], p32[g * 8 + 7]);
        *(uint4*)(QP + gt * 32 + g * 8) = st;
    }
}

extern "C" void kernel_launch(void* const* d_in, const int* in_sizes, int n_in,
                              void* d_out, int out_size, void* d_ws, size_t ws_size,
                              hipStream_t stream)
{
    (void)in_sizes; (void)n_in; (void)out_size; (void)ws_size;
    const int T1 = 50176, T2 = 12544;
    char* ws = (char*)d_ws;

    // ---- cursor-based workspace allocation (peak ~24.5 MB, known-safe) ----
    size_t cur = 0;
    auto alloc = [&](size_t bytes) {
        size_t r = cur; cur += (bytes + 127) & ~(size_t)127; return r;
    };
    static const int segIdx[28] = {0, 2, 3, 4, 5, 6, 7, 8, 9, 10, 11, 12, 13,
                                   14, 15, 16, 17, 18, 19, 20, 21, 22, 23, 24, 25, 26, 27, 28};
    static const int segN[28] = {1204224, 192, 4096, 64, 27, 27, 64, 64, 4096, 64, 4096, 64, 2048,
                                 110592, 192, 4096, 64, 576, 576, 64, 64, 4096, 64, 4096, 64, 2048,
                                 442368, 768};
    size_t segOff[28];
    for (int i = 0; i < 28; ++i) segOff[i] = alloc((size_t)segN[i] * 2);
    const size_t oMODE = alloc(256);
    const size_t oRED  = alloc(66560);             // 8 x 2080 fp32
    const size_t oBIG  = alloc(6422528);           // [T1,64]
    const size_t oKP   = alloc(3211264);           // [T1,32]
    const size_t oQP   = alloc(3211264);           // [T1,32]
    (void)oQP;

    bf16* P[28];
    for (int i = 0; i < 28; ++i) P[i] = (bf16*)(ws + segOff[i]);
    bf16* XC = P[0];
    bf16 *P1KQVB = P[1], *P1PW = P[2], *P1PB = P[3], *P1N1G = P[4], *P1N1B = P[5];
    bf16 *P1N2G = P[6], *P1N2B = P[7], *P1M1W = P[8], *P1M1B = P[9], *P1M2W = P[10];
    bf16 *P1M2B = P[11], *P1W = P[12];
    bf16 *P2KQVW = P[13], *P2KQVB = P[14], *P2PW = P[15], *P2PB = P[16];
    bf16 *P2N1G = P[17], *P2N1B = P[18], *P2N2G = P[19], *P2N2B = P[20];
    bf16 *P2M1W = P[21], *P2M1B = P[22], *P2M2W = P[23], *P2M2B = P[24], *P2W = P[25];
    bf16 *PROJW = P[26], *PROJB = P[27];

    int*   MODE = (int*)(ws + oMODE);
    float* REDF = (float*)(ws + oRED);
    bf16*  BIG  = (bf16*)(ws + oBIG);              // stage-1 V/Y/OUT (in-place chain)
    bf16*  KP   = (bf16*)(ws + oKP);
    bf16*  QP   = (bf16*)(ws + oKP + 3211264);
    bf16*  A2   = (bf16*)(ws + oKP);               // [T2,576] over dead KP/QP
    bf16*  KQV2F = (bf16*)d_out;                   // [8*T2,192] scratch in d_out
    bf16*  KP2F  = (bf16*)(ws + oKP);              // [8*T2,32]
    bf16*  QP2F  = (bf16*)(ws + oKP + 6422528);    // [8*T2,32]
    bf16*  YB2F  = (bf16*)(ws + oBIG);             // [8*T2,64] (over BIG, dead)
    bf16*  A3c   = (bf16*)(ws + oBIG + 12845056);  // [6272,576] chunk

    // ---- prologue: sniff dtype, convert all inputs to bf16 in ws ----
    k_sniff<<<1, 256, 0, stream>>>(d_in[0], MODE);
    CvTab tab;
    int cum = 0;
    for (int i = 0; i < 28; ++i) {
        tab.src[i] = d_in[segIdx[i]];
        tab.dstOff[i] = (int)(segOff[i] / 2);
        tab.cum[i] = cum;
        cum += segN[i];
    }
    tab.cum[28] = cum;
    k_convert_all<<<(cum + 255) / 256, 256, 0, stream>>>(tab, (bf16*)ws, MODE);

    // ---- per-batch: stage 1 + stage-2 front (unfold + kqv GEMM into d_out) ----
    for (int b = 0; b < 8; ++b) {
        float* REDb = REDF + (ll)b * 2080;
        k_fused1<<<196, 256, 0, stream>>>(XC, d_in[1], P1KQVB, P1N1G, P1N1B, P1W,
                                          MODE, KP, QP, BIG, REDb, b);
        k_reduce<<<dim3(196, 1), 256, 0, stream>>>(KP, BIG, 64, T1, REDb, 256);
        k_posta<<<dim3(196, 1), 256, 0, stream>>>(QP, REDb, BIG, 64, P1PW, P1PB,
                                                  BIG, T1);
        k_mlpln<<<784, 256, 0, stream>>>(BIG, P1N2G, P1N2B, P1M1W, P1M1B,
                                         P1M2W, P1M2B, BIG, BIG);
        k_unfold576<<<dim3(3136, 1), 256, 0, stream>>>(BIG, 224, 112, P2N1G, P2N1B,
                                                       1, A2, 0, 0);
        k_gemm<<<dim3(196, 3), 256, 0, stream>>>(A2, 576, P2KQVW, P2KQVB,
            nullptr, 0, KQV2F, 192, (ll)b * T2, 576, nullptr);
    }

    // ---- batched stage-2 tail (all 8 batches) ----
    k_fusedP2<<<dim3(49, 8), 256, 0, stream>>>(KQV2F, P2W, KP2F, QP2F, REDF, T2);
    k_reduce<<<dim3(49, 8), 256, 0, stream>>>(KP2F, KQV2F + 128, 192, T2, REDF, 256);
    k_posta<<<dim3(49, 8), 256, 0, stream>>>(QP2F, REDF, KQV2F + 128, 192,
                                             P2PW, P2PB, YB2F, T2);
    k_mlpln<<<1568, 256, 0, stream>>>(YB2F, P2N2G, P2N2B, P2M1W, P2M1B,
                                      P2M2W, P2M2B, YB2F, YB2F);

    // ---- epilogue: stage-3 unfold + final projection (KQV2F scratch now dead) ----
    for (int c = 0; c < 4; ++c) {
        k_unfold576<<<dim3(784, 2), 256, 0, stream>>>(
            YB2F + (ll)(2 * c) * T2 * 64, 112, 56, nullptr, nullptr, 0,
            A3c, (ll)T2 * 64, (ll)3136 * 576);
        k_gemm<<<dim3(98, 12), 256, 0, stream>>>(A3c, 576, PROJW, PROJB,
            nullptr, 0, d_out, 768, (ll)c * 6272, 576, MODE);
    }
}